// Round 2
// baseline (113.392 us; speedup 1.0000x reference)
//
#include <hip/hip_runtime.h>

constexpr int IMG_H = 128;
constexpr int IMG_W = 128;
constexpr int N_IMG = 4;
constexpr int CXCH = 3;
constexpr int CYCH = 21;
constexpr int RAD = 5;
constexpr int DIA = 11;                  // 2R+1
constexpr int TILE_H = 8;
constexpr int TILE_W = 16;
constexpr int PT_H = TILE_H + 2 * RAD;   // 18
constexpr int PT_W = TILE_W + 2 * RAD;   // 26
constexpr int NPIX = PT_H * PT_W;        // 468
constexpr int PSTR = 28;                 // padded floats/pixel: 2-way banks only
constexpr int NWAVES = 12;               // wave (di, half): di=0..5, col-half 0/1
constexpr int NTHREADS = NWAVES * 64;    // 768
constexpr int HW = IMG_H * IMG_W;

// Loss = (1/NHW) * sum_{n,p,delta} kval * (1 - y_p . y_{p+delta})
// kval = exp(-(di^2+dj^2)/72) * (0.9*exp(-50*|dx|^2) + 0.1)
// In-bounds pairs symmetric -> 60 half-window offsets, doubled.
// OOB (zero-pad) offsets folded analytically per pixel.
// R4: R3 was latency-bound, not LDS-throughput-bound (1.82x LDS cut -> no
// gain). Keep column-sharing (thread owns 2 adjacent centers in regs; one
// 96B column read feeds 2 pair terms) but split each di-row across 2 waves
// (6 cols each): 12 waves x 64 = 768 thr, 2 blocks/CU -> 6 waves/SIMD
// (was 3), per-wave chain 23 -> 11 terms, staging 2 rounds -> 1.
__device__ __forceinline__ float pair_term(
    const float* __restrict__ yc, const float* __restrict__ xc,
    const float4 q0, const float4 q1, const float4 q2,
    const float4 q3, const float4 q4, const float4 q5, float e1) {
    float dot = q5.x * yc[20];
    dot += q0.x * yc[0]  + q0.y * yc[1]  + q0.z * yc[2]  + q0.w * yc[3];
    dot += q1.x * yc[4]  + q1.y * yc[5]  + q1.z * yc[6]  + q1.w * yc[7];
    dot += q2.x * yc[8]  + q2.y * yc[9]  + q2.z * yc[10] + q2.w * yc[11];
    dot += q3.x * yc[12] + q3.y * yc[13] + q3.z * yc[14] + q3.w * yc[15];
    dot += q4.x * yc[16] + q4.y * yc[17] + q4.z * yc[18] + q4.w * yc[19];
    float d0 = q5.y - xc[0], d1 = q5.z - xc[1], d2 = q5.w - xc[2];
    float s2 = d0 * d0 + d1 * d1 + d2 * d2;
    float kv = e1 * (0.9f * __expf(-50.0f * s2) + 0.1f);
    return kv * (1.0f - dot);
}

#define LOADQ(nb)                              \
    float4 q0 = *(const float4*)&(nb)[0];      \
    float4 q1 = *(const float4*)&(nb)[4];      \
    float4 q2 = *(const float4*)&(nb)[8];      \
    float4 q3 = *(const float4*)&(nb)[12];     \
    float4 q4 = *(const float4*)&(nb)[16];     \
    float4 q5 = *(const float4*)&(nb)[20];

__global__ __launch_bounds__(NTHREADS, 6)
void gcrf_kernel(const float* __restrict__ x, const float* __restrict__ y,
                 float* __restrict__ out) {
    __shared__ __align__(16) float s[NPIX * PSTR];   // 52,416 B
    __shared__ float s_red[NWAVES];

    const int tid = threadIdx.x;
    const int n = blockIdx.z;
    const int h0 = blockIdx.y * TILE_H;
    const int w0 = blockIdx.x * TILE_W;

    const float* xb = x + (size_t)n * CXCH * HW;
    const float* yb = y + (size_t)n * CYCH * HW;

    // Stage padded tile (single round: 768 threads >= 468 pixels).
    // Layout per pixel: [y0..y19 | y20 x0 x1 x2 | pad*4]
    if (tid < NPIX) {
        int p = tid;
        int ti = p / PT_W, tj = p - ti * PT_W;
        int gh = h0 + ti - RAD, gw = w0 + tj - RAD;
        bool inb = ((unsigned)gh < (unsigned)IMG_H) &&
                   ((unsigned)gw < (unsigned)IMG_W);
        int gofs = gh * IMG_W + gw;
        float v[CYCH];
        #pragma unroll
        for (int c = 0; c < CYCH; c++) v[c] = inb ? yb[c * HW + gofs] : 0.0f;
        float xv[CXCH];
        #pragma unroll
        for (int c = 0; c < CXCH; c++) xv[c] = inb ? xb[c * HW + gofs] : 0.0f;
        float* d = &s[p * PSTR];
        #pragma unroll
        for (int q = 0; q < 5; q++)
            *(float4*)&d[q * 4] = make_float4(v[q * 4 + 0], v[q * 4 + 1],
                                              v[q * 4 + 2], v[q * 4 + 3]);
        *(float4*)&d[20] = make_float4(v[20], xv[0], xv[1], xv[2]);
    }
    __syncthreads();

    const int g = tid >> 6;              // wave id
    const int lane = tid & 63;
    const int di = g >> 1;               // window row 0..5
    const int hh = g & 1;                // column half 0/1
    const int row = lane >> 3;           // 0..7
    const int cs = lane & 7;             // centers 2cs, 2cs+1
    const int h = h0 + row;
    const int wA = w0 + 2 * cs;
    const int cp = (row + RAD) * PT_W + (2 * cs + RAD);

    // centers in registers (2 pixels x (21 y + 3 x))
    float ycA[CYCH], ycB[CYCH], xcA[CXCH], xcB[CXCH];
    {
        const float* a = &s[cp * PSTR];
        const float* b = a + PSTR;
        #pragma unroll
        for (int q = 0; q < 5; q++) {
            float4 t = *(const float4*)&a[q * 4];
            ycA[q * 4 + 0] = t.x; ycA[q * 4 + 1] = t.y;
            ycA[q * 4 + 2] = t.z; ycA[q * 4 + 3] = t.w;
            float4 u = *(const float4*)&b[q * 4];
            ycB[q * 4 + 0] = u.x; ycB[q * 4 + 1] = u.y;
            ycB[q * 4 + 2] = u.z; ycB[q * 4 + 3] = u.w;
        }
        float4 t = *(const float4*)&a[20];
        ycA[20] = t.x; xcA[0] = t.y; xcA[1] = t.z; xcA[2] = t.w;
        float4 u = *(const float4*)&b[20];
        ycB[20] = u.x; xcB[0] = u.y; xcB[1] = u.z; xcB[2] = u.w;
    }

    const bool rowok = (h + di) < IMG_H;
    const float erow = __expf(-(float)(di * di) * (1.0f / 72.0f));
    // exp(-dj*dj/72) -- all indices below are compile-time constants
    constexpr float EDJ[6] = {1.0f, 0.98620695f, 0.94595945f,
                              0.88249690f, 0.80073744f, 0.70664826f};

    float acco = 0.0f;   // single-counted OOB fold
    float accp = 0.0f;   // half-window pair terms (doubled at the end)

    if (g == 0) {
        // (di=0, half 0) has no valid half-window columns -> OOB fold duty
        #pragma unroll
        for (int i = 0; i < 2; i++) {
            int ww = wA + i;
            const float* xc = i ? xcB : xcA;
            int i0 = max(0, RAD - h), i1 = min(DIA - 1, IMG_H - 1 - h + RAD);
            int j0 = max(0, RAD - ww), j1 = min(DIA - 1, IMG_W - 1 - ww + RAD);
            int n_oob = DIA * DIA - (i1 - i0 + 1) * (j1 - j0 + 1);
            if (n_oob > 0) {
                float oxy = (float)(h * h + ww * ww) * (1.0f / 36.0f);
                float s2c = xc[0] * xc[0] + xc[1] * xc[1] + xc[2] * xc[2];
                float kvo = __expf(-0.5f * oxy) *
                            (0.9f * __expf(-50.0f * s2c) + 0.1f);
                acco += (float)n_oob * kvo;
            }
        }
    } else if (hh == 0) {
        // columns j=0..5 (col offset t-5): A dj=t-5 in [-5,0], B dj=t-6
        #pragma unroll
        for (int t = 0; t < 6; t++) {
            const float* nb = &s[(cp + di * PT_W + (t - 5)) * PSTR];
            LOADQ(nb);
            int gc = wA + (t - 5);
            float f = (rowok && (unsigned)gc < (unsigned)IMG_W) ? erow : 0.0f;
            accp += pair_term(ycA, xcA, q0, q1, q2, q3, q4, q5, f * EDJ[5 - t]);
            if (t >= 1)
                accp += pair_term(ycB, xcB, q0, q1, q2, q3, q4, q5,
                                  f * EDJ[6 - t]);
        }
    } else {
        // columns j=6..11 (col offset t+1): A dj=t+1 in [1,5], B dj=t
        #pragma unroll
        for (int t = 0; t < 6; t++) {
            const float* nb = &s[(cp + di * PT_W + (t + 1)) * PSTR];
            LOADQ(nb);
            int gc = wA + t + 1;
            float f = (rowok && (unsigned)gc < (unsigned)IMG_W) ? erow : 0.0f;
            if (t <= 4)
                accp += pair_term(ycA, xcA, q0, q1, q2, q3, q4, q5,
                                  f * EDJ[t + 1]);
            if (t >= 1)
                accp += pair_term(ycB, xcB, q0, q1, q2, q3, q4, q5, f * EDJ[t]);
            else if (di > 0)   // t=0: B dj=0 valid only for di>=1
                accp += pair_term(ycB, xcB, q0, q1, q2, q3, q4, q5, f * EDJ[0]);
        }
    }

    float total = acco + 2.0f * accp;

    // block reduce -> one atomic per block
    #pragma unroll
    for (int sft = 32; sft > 0; sft >>= 1)
        total += __shfl_down(total, sft, 64);
    if (lane == 0) s_red[g] = total;
    __syncthreads();
    if (tid == 0) {
        float bs = 0.0f;
        #pragma unroll
        for (int wv = 0; wv < NWAVES; wv++) bs += s_red[wv];
        atomicAdd(out, bs * (1.0f / (float)(N_IMG * HW)));
    }
}

extern "C" void kernel_launch(void* const* d_in, const int* in_sizes, int n_in,
                              void* d_out, int out_size, void* d_ws, size_t ws_size,
                              hipStream_t stream) {
    const float* x = (const float*)d_in[0];
    const float* y = (const float*)d_in[1];
    float* out = (float*)d_out;
    hipMemsetAsync(out, 0, sizeof(float), stream);
    dim3 grid(IMG_W / TILE_W, IMG_H / TILE_H, N_IMG);  // (8,16,4) = 512 blocks
    gcrf_kernel<<<grid, NTHREADS, 0, stream>>>(x, y, out);
}

// Round 3
// 97.530 us; speedup vs baseline: 1.1626x; 1.1626x over previous
//
#include <hip/hip_runtime.h>

constexpr int IMG_H = 128;
constexpr int IMG_W = 128;
constexpr int N_IMG = 4;
constexpr int CXCH = 3;
constexpr int CYCH = 21;
constexpr int RAD = 5;
constexpr int DIA = 11;                  // 2R+1
constexpr int TILE_H = 8;
constexpr int TILE_W = 16;
constexpr int PT_H = TILE_H + 2 * RAD;   // 18
constexpr int PT_W = TILE_W + 2 * RAD;   // 26
constexpr int NPIX = PT_H * PT_W;        // 468
constexpr int PSTR = 28;                 // padded floats/pixel
constexpr int NWAVES = 12;               // wave (di, half): di=0..5, col-half 0/1
constexpr int NTHREADS = NWAVES * 64;    // 768
constexpr int HW = IMG_H * IMG_W;

// Loss = (1/NHW) * sum_{n,p,delta} kval * (1 - y_p . y_{p+delta})
// kval = exp(-(di^2+dj^2)/72) * (0.9*exp(-50*|dx|^2) + 0.1)
// In-bounds pairs symmetric -> 60 half-window offsets, doubled.
// OOB (zero-pad) offsets folded analytically per pixel.
// R5: R4's 54us kernel was a scratch-spill benchmark (VGPR=40, 101MB
// WRITE_SIZE = center arrays demoted to local mem via runtime pointer
// select + pointer-passed arrays, rule #20). This round: centers are
// explicit float4 locals (A0..A5, B0..B5), pair_term takes float4s BY
// VALUE, OOB fold duplicated for A/B. Structure otherwise identical to
// R4 (12 waves, column-sharing, single-round staging).
__device__ __forceinline__ float pair_term(
    const float4 c0, const float4 c1, const float4 c2,
    const float4 c3, const float4 c4, const float4 c5,
    const float4 q0, const float4 q1, const float4 q2,
    const float4 q3, const float4 q4, const float4 q5, float e1) {
    float dot = q5.x * c5.x;
    dot += q0.x * c0.x + q0.y * c0.y + q0.z * c0.z + q0.w * c0.w;
    dot += q1.x * c1.x + q1.y * c1.y + q1.z * c1.z + q1.w * c1.w;
    dot += q2.x * c2.x + q2.y * c2.y + q2.z * c2.z + q2.w * c2.w;
    dot += q3.x * c3.x + q3.y * c3.y + q3.z * c3.z + q3.w * c3.w;
    dot += q4.x * c4.x + q4.y * c4.y + q4.z * c4.z + q4.w * c4.w;
    float d0 = q5.y - c5.y, d1 = q5.z - c5.z, d2 = q5.w - c5.w;
    float s2 = d0 * d0 + d1 * d1 + d2 * d2;
    float kv = e1 * (0.9f * __expf(-50.0f * s2) + 0.1f);
    return kv * (1.0f - dot);
}

#define LOADQ(nb)                              \
    float4 q0 = *(const float4*)&(nb)[0];      \
    float4 q1 = *(const float4*)&(nb)[4];      \
    float4 q2 = *(const float4*)&(nb)[8];      \
    float4 q3 = *(const float4*)&(nb)[12];     \
    float4 q4 = *(const float4*)&(nb)[16];     \
    float4 q5 = *(const float4*)&(nb)[20];

__global__ __launch_bounds__(NTHREADS, 6)
void gcrf_kernel(const float* __restrict__ x, const float* __restrict__ y,
                 float* __restrict__ out) {
    __shared__ __align__(16) float s[NPIX * PSTR];   // 52,416 B
    __shared__ float s_red[NWAVES];

    const int tid = threadIdx.x;
    const int n = blockIdx.z;
    const int h0 = blockIdx.y * TILE_H;
    const int w0 = blockIdx.x * TILE_W;

    const float* xb = x + (size_t)n * CXCH * HW;
    const float* yb = y + (size_t)n * CYCH * HW;

    // Stage padded tile (single round: 768 threads >= 468 pixels).
    // Layout per pixel: [y0..y19 | y20 x0 x1 x2 | pad*4]
    if (tid < NPIX) {
        int p = tid;
        int ti = p / PT_W, tj = p - ti * PT_W;
        int gh = h0 + ti - RAD, gw = w0 + tj - RAD;
        bool inb = ((unsigned)gh < (unsigned)IMG_H) &&
                   ((unsigned)gw < (unsigned)IMG_W);
        int gofs = gh * IMG_W + gw;
        float v[CYCH];
        #pragma unroll
        for (int c = 0; c < CYCH; c++) v[c] = inb ? yb[c * HW + gofs] : 0.0f;
        float xv[CXCH];
        #pragma unroll
        for (int c = 0; c < CXCH; c++) xv[c] = inb ? xb[c * HW + gofs] : 0.0f;
        float* d = &s[p * PSTR];
        #pragma unroll
        for (int q = 0; q < 5; q++)
            *(float4*)&d[q * 4] = make_float4(v[q * 4 + 0], v[q * 4 + 1],
                                              v[q * 4 + 2], v[q * 4 + 3]);
        *(float4*)&d[20] = make_float4(v[20], xv[0], xv[1], xv[2]);
    }
    __syncthreads();

    const int g = tid >> 6;              // wave id
    const int lane = tid & 63;
    const int di = g >> 1;               // window row 0..5
    const int hh = g & 1;                // column half 0/1
    const int row = lane >> 3;           // 0..7
    const int cs = lane & 7;             // centers 2cs, 2cs+1
    const int h = h0 + row;
    const int wA = w0 + 2 * cs;
    const int cp = (row + RAD) * PT_W + (2 * cs + RAD);

    // centers as explicit float4 locals -- fully static access, stays in VGPRs
    const float* ca = &s[cp * PSTR];
    const float4 A0 = *(const float4*)&ca[0];
    const float4 A1 = *(const float4*)&ca[4];
    const float4 A2 = *(const float4*)&ca[8];
    const float4 A3 = *(const float4*)&ca[12];
    const float4 A4 = *(const float4*)&ca[16];
    const float4 A5 = *(const float4*)&ca[20];        // {y20, x0, x1, x2}
    const float4 B0 = *(const float4*)&ca[PSTR + 0];
    const float4 B1 = *(const float4*)&ca[PSTR + 4];
    const float4 B2 = *(const float4*)&ca[PSTR + 8];
    const float4 B3 = *(const float4*)&ca[PSTR + 12];
    const float4 B4 = *(const float4*)&ca[PSTR + 16];
    const float4 B5 = *(const float4*)&ca[PSTR + 20];

    const bool rowok = (h + di) < IMG_H;
    const float erow = __expf(-(float)(di * di) * (1.0f / 72.0f));
    // exp(-dj*dj/72) -- all indices below are compile-time constants
    constexpr float EDJ[6] = {1.0f, 0.98620695f, 0.94595945f,
                              0.88249690f, 0.80073744f, 0.70664826f};

    float acco = 0.0f;   // single-counted OOB fold
    float accp = 0.0f;   // half-window pair terms (doubled at the end)

    if (g == 0) {
        // (di=0, half 0) has no valid half-window columns -> OOB fold duty.
        // Written out twice (A then B) -- no runtime pointer select.
        int i0 = max(0, RAD - h), i1 = min(DIA - 1, IMG_H - 1 - h + RAD);
        int nrow = i1 - i0 + 1;
        {   // center A (col wA)
            int j0 = max(0, RAD - wA), j1 = min(DIA - 1, IMG_W - 1 - wA + RAD);
            int n_oob = DIA * DIA - nrow * (j1 - j0 + 1);
            if (n_oob > 0) {
                float oxy = (float)(h * h + wA * wA) * (1.0f / 36.0f);
                float s2c = A5.y * A5.y + A5.z * A5.z + A5.w * A5.w;
                acco += (float)n_oob * __expf(-0.5f * oxy) *
                        (0.9f * __expf(-50.0f * s2c) + 0.1f);
            }
        }
        {   // center B (col wA+1)
            int wB = wA + 1;
            int j0 = max(0, RAD - wB), j1 = min(DIA - 1, IMG_W - 1 - wB + RAD);
            int n_oob = DIA * DIA - nrow * (j1 - j0 + 1);
            if (n_oob > 0) {
                float oxy = (float)(h * h + wB * wB) * (1.0f / 36.0f);
                float s2c = B5.y * B5.y + B5.z * B5.z + B5.w * B5.w;
                acco += (float)n_oob * __expf(-0.5f * oxy) *
                        (0.9f * __expf(-50.0f * s2c) + 0.1f);
            }
        }
    } else if (hh == 0) {
        // columns j=0..5 (col offset t-5): A dj=t-5 in [-5,0], B dj=t-6
        #pragma unroll
        for (int t = 0; t < 6; t++) {
            const float* nb = &s[(cp + di * PT_W + (t - 5)) * PSTR];
            LOADQ(nb);
            int gc = wA + (t - 5);
            float f = (rowok && (unsigned)gc < (unsigned)IMG_W) ? erow : 0.0f;
            accp += pair_term(A0, A1, A2, A3, A4, A5,
                              q0, q1, q2, q3, q4, q5, f * EDJ[5 - t]);
            if (t >= 1)
                accp += pair_term(B0, B1, B2, B3, B4, B5,
                                  q0, q1, q2, q3, q4, q5, f * EDJ[6 - t]);
        }
    } else {
        // columns j=6..11 (col offset t+1): A dj=t+1 in [1,5], B dj=t
        #pragma unroll
        for (int t = 0; t < 6; t++) {
            const float* nb = &s[(cp + di * PT_W + (t + 1)) * PSTR];
            LOADQ(nb);
            int gc = wA + t + 1;
            float f = (rowok && (unsigned)gc < (unsigned)IMG_W) ? erow : 0.0f;
            if (t <= 4)
                accp += pair_term(A0, A1, A2, A3, A4, A5,
                                  q0, q1, q2, q3, q4, q5, f * EDJ[t + 1]);
            if (t >= 1)
                accp += pair_term(B0, B1, B2, B3, B4, B5,
                                  q0, q1, q2, q3, q4, q5, f * EDJ[t]);
            else if (di > 0)   // t=0: B dj=0 valid only for di>=1
                accp += pair_term(B0, B1, B2, B3, B4, B5,
                                  q0, q1, q2, q3, q4, q5, f * EDJ[0]);
        }
    }

    float total = acco + 2.0f * accp;

    // block reduce -> one atomic per block
    #pragma unroll
    for (int sft = 32; sft > 0; sft >>= 1)
        total += __shfl_down(total, sft, 64);
    if (lane == 0) s_red[g] = total;
    __syncthreads();
    if (tid == 0) {
        float bs = 0.0f;
        #pragma unroll
        for (int wv = 0; wv < NWAVES; wv++) bs += s_red[wv];
        atomicAdd(out, bs * (1.0f / (float)(N_IMG * HW)));
    }
}

extern "C" void kernel_launch(void* const* d_in, const int* in_sizes, int n_in,
                              void* d_out, int out_size, void* d_ws, size_t ws_size,
                              hipStream_t stream) {
    const float* x = (const float*)d_in[0];
    const float* y = (const float*)d_in[1];
    float* out = (float*)d_out;
    hipMemsetAsync(out, 0, sizeof(float), stream);
    dim3 grid(IMG_W / TILE_W, IMG_H / TILE_H, N_IMG);  // (8,16,4) = 512 blocks
    gcrf_kernel<<<grid, NTHREADS, 0, stream>>>(x, y, out);
}

// Round 4
// 88.005 us; speedup vs baseline: 1.2885x; 1.1082x over previous
//
#include <hip/hip_runtime.h>

constexpr int IMG_H = 128;
constexpr int IMG_W = 128;
constexpr int N_IMG = 4;
constexpr int CXCH = 3;
constexpr int CYCH = 21;
constexpr int RAD = 5;
constexpr int DIA = 11;                  // 2R+1
constexpr int TILE_H = 8;
constexpr int TILE_W = 16;
constexpr int PT_H = TILE_H + 2 * RAD;   // 18
constexpr int PT_W = TILE_W + 2 * RAD;   // 26
constexpr int NPIX = PT_H * PT_W;        // 468
constexpr int PSTR = 32;                 // 8 slots x 4 words (chunk-XOR swizzle)
constexpr int NWAVES = 8;
constexpr int NTHREADS = NWAVES * 64;    // 512
constexpr int HW = IMG_H * IMG_W;

// Loss = (1/NHW) * sum_{n,p,delta} kval * (1 - y_p . y_{p+delta})
// kval = exp(-(di^2+dj^2)/72) * (0.9*exp(-50*|dx|^2) + 0.1)
// In-bounds pairs symmetric -> 60 half-window offsets, doubled; OOB folded
// analytically. Column-sharing: thread owns 2 adjacent centers (A,B) in
// explicit float4 locals; one 96B neighbor read feeds both centers' terms.
// R6 fixes vs R4/R5:
//  - launch_bounds(512,4): VGPR cap 128 (R5's (768,6) cap 85 forced spills)
//  - PSTR=32 + chunk-XOR swizzle slot=q^((p>>1)&7) on write AND read:
//    lanes step p by 2 -> (p>>1)&7 distinct per 8 lanes -> b128 reads cover
//    all 32 banks once (R4's PSTR=28 gave 16-way conflicts, 3.6M/dispatch)
//  - 66 shared columns as template<int C> instantiations: di/dj/weights/
//    validity constexpr, Gaussian xy weights from constexpr table
constexpr float KW[6][6] = {
    // exp(-(di*di+dj*dj)/72), di = row, |dj| = col
    {1.000000f, 0.986207f, 0.945959f, 0.882497f, 0.800737f, 0.706648f},
    {0.986207f, 0.972604f, 0.932912f, 0.870325f, 0.789694f, 0.696903f},
    {0.945959f, 0.932912f, 0.894839f, 0.834809f, 0.757465f, 0.668468f},
    {0.882497f, 0.870325f, 0.834809f, 0.778801f, 0.706648f, 0.623614f},
    {0.800737f, 0.789694f, 0.757465f, 0.706648f, 0.641180f, 0.565856f},
    {0.706648f, 0.696903f, 0.668468f, 0.623614f, 0.565856f, 0.499352f},
};

// Column c -> (di, j): c in [0,6) -> di=0, j=c+6 ; else di=1+(c-6)/12,
// j=(c-6)%12. Column j covers center A at dj=j-5 and center B at dj=j-6.
template<int C>
__device__ __forceinline__ float do_col(
    const float* __restrict__ s, int cp, int h, int wA,
    float4 A0, float4 A1, float4 A2, float4 A3, float4 A4, float4 A5,
    float4 B0, float4 B1, float4 B2, float4 B3, float4 B4, float4 B5) {
    constexpr int di  = (C < 6) ? 0 : 1 + (C - 6) / 12;
    constexpr int j   = (C < 6) ? C + 6 : (C - 6) % 12;
    constexpr int djA = j - 5, djB = j - 6;
    constexpr int aA  = djA < 0 ? -djA : djA;
    constexpr int aB  = djB < 0 ? -djB : djB;
    // half-window validity: di=0 uses only dj>=1; dj must be in [-5,5]
    constexpr bool vA = (j <= 10) && (di > 0 || djA >= 1);
    constexpr bool vB = (j >= 1)  && (di > 0 || djB >= 1);

    const int pn = cp + di * PT_W + djA;         // shared neighbor pixel
    const bool inb = ((h + di) < IMG_H) &&
                     ((unsigned)(wA + djA) < (unsigned)IMG_W);
    const int xs = (pn >> 1) & 7;
    const float* bp = s + pn * PSTR;
    const float4 q0 = *(const float4*)&bp[(0 ^ xs) << 2];
    const float4 q1 = *(const float4*)&bp[(1 ^ xs) << 2];
    const float4 q2 = *(const float4*)&bp[(2 ^ xs) << 2];
    const float4 q3 = *(const float4*)&bp[(3 ^ xs) << 2];
    const float4 q4 = *(const float4*)&bp[(4 ^ xs) << 2];
    const float4 q5 = *(const float4*)&bp[(5 ^ xs) << 2];  // {y20,x0,x1,x2}

    float res = 0.0f;
    if constexpr (vA) {
        float dot = q5.x * A5.x;
        dot += q0.x * A0.x + q0.y * A0.y + q0.z * A0.z + q0.w * A0.w;
        dot += q1.x * A1.x + q1.y * A1.y + q1.z * A1.z + q1.w * A1.w;
        dot += q2.x * A2.x + q2.y * A2.y + q2.z * A2.z + q2.w * A2.w;
        dot += q3.x * A3.x + q3.y * A3.y + q3.z * A3.z + q3.w * A3.w;
        dot += q4.x * A4.x + q4.y * A4.y + q4.z * A4.z + q4.w * A4.w;
        float d0 = q5.y - A5.y, d1 = q5.z - A5.z, d2 = q5.w - A5.w;
        float s2 = d0 * d0 + d1 * d1 + d2 * d2;
        float kv = (inb ? KW[di][aA] : 0.0f) *
                   (0.9f * __expf(-50.0f * s2) + 0.1f);
        res += kv * (1.0f - dot);
    }
    if constexpr (vB) {
        float dot = q5.x * B5.x;
        dot += q0.x * B0.x + q0.y * B0.y + q0.z * B0.z + q0.w * B0.w;
        dot += q1.x * B1.x + q1.y * B1.y + q1.z * B1.z + q1.w * B1.w;
        dot += q2.x * B2.x + q2.y * B2.y + q2.z * B2.z + q2.w * B2.w;
        dot += q3.x * B3.x + q3.y * B3.y + q3.z * B3.z + q3.w * B3.w;
        dot += q4.x * B4.x + q4.y * B4.y + q4.z * B4.z + q4.w * B4.w;
        float d0 = q5.y - B5.y, d1 = q5.z - B5.z, d2 = q5.w - B5.w;
        float s2 = d0 * d0 + d1 * d1 + d2 * d2;
        float kv = (inb ? KW[di][aB] : 0.0f) *
                   (0.9f * __expf(-50.0f * s2) + 0.1f);
        res += kv * (1.0f - dot);
    }
    return res;
}

__global__ __launch_bounds__(NTHREADS, 4)
void gcrf_kernel(const float* __restrict__ x, const float* __restrict__ y,
                 float* __restrict__ out) {
    __shared__ __align__(16) float s[NPIX * PSTR];   // 59,904 B
    __shared__ float s_red[NWAVES];

    const int tid = threadIdx.x;
    const int n = blockIdx.z;
    const int h0 = blockIdx.y * TILE_H;
    const int w0 = blockIdx.x * TILE_W;

    const float* xb = x + (size_t)n * CXCH * HW;
    const float* yb = y + (size_t)n * CYCH * HW;

    // Stage padded tile, single round (512 >= 468). Per pixel: 6 swizzled
    // 16B chunks: q0..q4 = y0..y19, q5 = {y20, x0, x1, x2}.
    if (tid < NPIX) {
        int p = tid;
        int ti = p / PT_W, tj = p - ti * PT_W;
        int gh = h0 + ti - RAD, gw = w0 + tj - RAD;
        bool inb = ((unsigned)gh < (unsigned)IMG_H) &&
                   ((unsigned)gw < (unsigned)IMG_W);
        int gofs = gh * IMG_W + gw;
        float v[CYCH];
        #pragma unroll
        for (int c = 0; c < CYCH; c++) v[c] = inb ? yb[c * HW + gofs] : 0.0f;
        float xv[CXCH];
        #pragma unroll
        for (int c = 0; c < CXCH; c++) xv[c] = inb ? xb[c * HW + gofs] : 0.0f;
        int xs = (p >> 1) & 7;
        float* d = &s[p * PSTR];
        #pragma unroll
        for (int q = 0; q < 5; q++)
            *(float4*)&d[(q ^ xs) << 2] =
                make_float4(v[q * 4 + 0], v[q * 4 + 1],
                            v[q * 4 + 2], v[q * 4 + 3]);
        *(float4*)&d[(5 ^ xs) << 2] = make_float4(v[20], xv[0], xv[1], xv[2]);
    }
    __syncthreads();

    const int wid = tid >> 6;            // wave id -> column range
    const int lane = tid & 63;
    const int row = lane >> 3;           // 0..7
    const int cs = lane & 7;             // centers 2cs, 2cs+1
    const int h = h0 + row;
    const int wA = w0 + 2 * cs;
    const int cp = (row + RAD) * PT_W + (2 * cs + RAD);

    // centers as explicit float4 locals (swizzled read, same formula)
    const float* ca = &s[cp * PSTR];
    const int xa = (cp >> 1) & 7;
    const float4 A0 = *(const float4*)&ca[(0 ^ xa) << 2];
    const float4 A1 = *(const float4*)&ca[(1 ^ xa) << 2];
    const float4 A2 = *(const float4*)&ca[(2 ^ xa) << 2];
    const float4 A3 = *(const float4*)&ca[(3 ^ xa) << 2];
    const float4 A4 = *(const float4*)&ca[(4 ^ xa) << 2];
    const float4 A5 = *(const float4*)&ca[(5 ^ xa) << 2];
    const float* cb = ca + PSTR;
    const int xbn = ((cp + 1) >> 1) & 7;
    const float4 B0 = *(const float4*)&cb[(0 ^ xbn) << 2];
    const float4 B1 = *(const float4*)&cb[(1 ^ xbn) << 2];
    const float4 B2 = *(const float4*)&cb[(2 ^ xbn) << 2];
    const float4 B3 = *(const float4*)&cb[(3 ^ xbn) << 2];
    const float4 B4 = *(const float4*)&cb[(4 ^ xbn) << 2];
    const float4 B5 = *(const float4*)&cb[(5 ^ xbn) << 2];

    #define DC(C) do_col<C>(s, cp, h, wA, A0, A1, A2, A3, A4, A5, \
                            B0, B1, B2, B3, B4, B5)

    float accp = 0.0f;   // half-window pair terms (doubled at the end)
    float acco = 0.0f;   // single-counted OOB fold
    switch (wid) {
    case 0: accp = DC(0)+DC(1)+DC(2)+DC(3)+DC(4)+DC(5)+DC(6)+DC(7)+DC(8);
        break;
    case 1: accp = DC(9)+DC(10)+DC(11)+DC(12)+DC(13)+DC(14)+DC(15)+DC(16);
        break;
    case 2: accp = DC(17)+DC(18)+DC(19)+DC(20)+DC(21)+DC(22)+DC(23)+DC(24);
        break;
    case 3: accp = DC(25)+DC(26)+DC(27)+DC(28)+DC(29)+DC(30)+DC(31)+DC(32);
        break;
    case 4: accp = DC(33)+DC(34)+DC(35)+DC(36)+DC(37)+DC(38)+DC(39)+DC(40)
                 + DC(41);
        break;
    case 5: accp = DC(42)+DC(43)+DC(44)+DC(45)+DC(46)+DC(47)+DC(48)+DC(49);
        break;
    case 6: accp = DC(50)+DC(51)+DC(52)+DC(53)+DC(54)+DC(55)+DC(56)+DC(57);
        break;
    case 7: {
        accp = DC(58)+DC(59)+DC(60)+DC(61)+DC(62)+DC(63)+DC(64)+DC(65);
        // analytic OOB fold, A then B (no runtime pointer select)
        int i0 = max(0, RAD - h), i1 = min(DIA - 1, IMG_H - 1 - h + RAD);
        int nrow = i1 - i0 + 1;
        {
            int j0 = max(0, RAD - wA), j1 = min(DIA - 1, IMG_W - 1 - wA + RAD);
            int n_oob = DIA * DIA - nrow * (j1 - j0 + 1);
            if (n_oob > 0) {
                float oxy = (float)(h * h + wA * wA) * (1.0f / 36.0f);
                float s2c = A5.y * A5.y + A5.z * A5.z + A5.w * A5.w;
                acco += (float)n_oob * __expf(-0.5f * oxy) *
                        (0.9f * __expf(-50.0f * s2c) + 0.1f);
            }
        }
        {
            int wB = wA + 1;
            int j0 = max(0, RAD - wB), j1 = min(DIA - 1, IMG_W - 1 - wB + RAD);
            int n_oob = DIA * DIA - nrow * (j1 - j0 + 1);
            if (n_oob > 0) {
                float oxy = (float)(h * h + wB * wB) * (1.0f / 36.0f);
                float s2c = B5.y * B5.y + B5.z * B5.z + B5.w * B5.w;
                acco += (float)n_oob * __expf(-0.5f * oxy) *
                        (0.9f * __expf(-50.0f * s2c) + 0.1f);
            }
        }
        break;
    }
    }
    #undef DC

    float total = acco + 2.0f * accp;

    // block reduce -> one atomic per block
    #pragma unroll
    for (int sft = 32; sft > 0; sft >>= 1)
        total += __shfl_down(total, sft, 64);
    if (lane == 0) s_red[wid] = total;
    __syncthreads();
    if (tid == 0) {
        float bs = 0.0f;
        #pragma unroll
        for (int wv = 0; wv < NWAVES; wv++) bs += s_red[wv];
        atomicAdd(out, bs * (1.0f / (float)(N_IMG * HW)));
    }
}

extern "C" void kernel_launch(void* const* d_in, const int* in_sizes, int n_in,
                              void* d_out, int out_size, void* d_ws, size_t ws_size,
                              hipStream_t stream) {
    const float* x = (const float*)d_in[0];
    const float* y = (const float*)d_in[1];
    float* out = (float*)d_out;
    hipMemsetAsync(out, 0, sizeof(float), stream);
    dim3 grid(IMG_W / TILE_W, IMG_H / TILE_H, N_IMG);  // (8,16,4) = 512 blocks
    gcrf_kernel<<<grid, NTHREADS, 0, stream>>>(x, y, out);
}

// Round 5
// 78.498 us; speedup vs baseline: 1.4445x; 1.1211x over previous
//
#include <hip/hip_runtime.h>

constexpr int IMG_H = 128;
constexpr int IMG_W = 128;
constexpr int N_IMG = 4;
constexpr int CXCH = 3;
constexpr int CYCH = 21;
constexpr int RAD = 5;
constexpr int DIA = 11;                    // 2R+1
constexpr int TILE_H = 8;
constexpr int TILE_W = 16;
constexpr int PT_H = TILE_H + 2 * RAD;     // 18
constexpr int PT_W = TILE_W + 2 * RAD;     // 26
constexpr int NPIX = PT_H * PT_W;          // 468
constexpr int NPIXT = TILE_H * TILE_W;     // 128 pixels per block
constexpr int NGROUP = 4;                  // offset-split factor
constexpr int NTHREADS = NPIXT * NGROUP;   // 512
constexpr int NPAIR = 60;                  // half-window offsets (doubled)
constexpr int PPG = NPAIR / NGROUP;        // 15 pairs per thread
constexpr int HW = IMG_H * IMG_W;

// Loss = (1/NHW) * sum_{n,p,delta} kval(p,delta) * (1 - y_p . y_{p+delta})
//   kval = 0.9*exp(-0.5*(xy + 100*|dx|^2)) + 0.1*exp(-0.5*xy)
// Symmetry: in-bounds pair terms symmetric -> 60 half-window offsets, x2.
// OOB (zero-pad) offsets have identical kval per pixel -> analytic fold.
// R2: 4-way offset split -> 4 waves/SIMD (was 1) to hide ds_read latency;
//     per-thread chain 60 -> 15 fully unrolled pair terms.
// R7: reverted to this variant verbatim. R3-R6 (column-sharing: thread
//     owns 2 centers in regs, one neighbor read feeds 2 pair terms) all
//     lost to VGPR spills (R4: VGPR=40/101MB scratch; R6: VGPR=64/22MB
//     scratch, 27us vs this kernel's 16us). The LDS-traffic win (~3us)
//     is smaller than the cheapest observed spill penalty (~10us).
__global__ __launch_bounds__(NTHREADS, 4)
void gcrf_kernel(const float* __restrict__ x, const float* __restrict__ y,
                 float* __restrict__ out) {
    __shared__ __align__(16) float sy[NPIX * 20];  // y ch 0..19, [pix][20]
    __shared__ __align__(16) float sx[NPIX * 4];   // {x0,x1,x2,y20} [pix][4]
    __shared__ int   s_pk[NPAIR];                  // (di<<8) | (dj+8)
    __shared__ float s_e1[NPAIR];                  // exp(-(di^2+dj^2)/72)
    __shared__ float s_red[NTHREADS / 64];

    const int tid = threadIdx.x;
    const int n = blockIdx.z;
    const int h0 = blockIdx.y * TILE_H;
    const int w0 = blockIdx.x * TILE_W;

    const float* xb = x + (size_t)n * CXCH * HW;
    const float* yb = y + (size_t)n * CYCH * HW;

    // pair table: k=0..4 -> (0, 1..5); k=5..59 -> (1+m/11, m%11-5)
    if (tid < NPAIR) {
        int di, dj;
        if (tid < 5) { di = 0; dj = tid + 1; }
        else         { int m = tid - 5; di = 1 + m / 11; dj = m % 11 - 5; }
        s_pk[tid] = (di << 8) | (dj + 8);
        s_e1[tid] = __expf(-0.5f * (float)(di * di + dj * dj) * (1.0f / 36.0f));
    }

    // Stage padded tile: zeros outside image (zero-pad unfold semantics)
    for (int p = tid; p < NPIX; p += NTHREADS) {
        int ti = p / PT_W, tj = p - ti * PT_W;
        int gh = h0 + ti - RAD, gw = w0 + tj - RAD;
        bool inb = ((unsigned)gh < (unsigned)IMG_H) && ((unsigned)gw < (unsigned)IMG_W);
        int gofs = gh * IMG_W + gw;
        float v[CYCH];
        #pragma unroll
        for (int c = 0; c < CYCH; c++) v[c] = inb ? yb[c * HW + gofs] : 0.0f;
        float xv[CXCH];
        #pragma unroll
        for (int c = 0; c < CXCH; c++) xv[c] = inb ? xb[c * HW + gofs] : 0.0f;
        #pragma unroll
        for (int q = 0; q < 5; q++) {
            *(float4*)&sy[p * 20 + q * 4] =
                make_float4(v[q * 4 + 0], v[q * 4 + 1], v[q * 4 + 2], v[q * 4 + 3]);
        }
        *(float4*)&sx[p * 4] = make_float4(xv[0], xv[1], xv[2], v[20]);
    }
    __syncthreads();

    const int g = tid >> 7;          // offset group 0..3 (wave-uniform)
    const int pix = tid & (NPIXT - 1);
    const int tx = pix & (TILE_W - 1);
    const int ty = pix >> 4;
    const int h = h0 + ty, w = w0 + tx;
    const int cp = (ty + RAD) * PT_W + (tx + RAD);

    const float4 cx4 = *(const float4*)&sx[cp * 4];
    float yc[20];
    #pragma unroll
    for (int q = 0; q < 5; q++) {
        float4 t = *(const float4*)&sy[cp * 20 + q * 4];
        yc[q * 4 + 0] = t.x; yc[q * 4 + 1] = t.y;
        yc[q * 4 + 2] = t.z; yc[q * 4 + 3] = t.w;
    }

    // ---- OOB analytic fold (one-sided, not doubled; group 0 only) ----
    float acc = 0.0f;
    if (g == 0) {
        int i0 = max(0, RAD - h), i1 = min(DIA - 1, IMG_H - 1 - h + RAD);
        int j0 = max(0, RAD - w), j1 = min(DIA - 1, IMG_W - 1 - w + RAD);
        int n_oob = DIA * DIA - (i1 - i0 + 1) * (j1 - j0 + 1);
        if (n_oob > 0) {
            float oxy = (float)(h * h + w * w) * (1.0f / 36.0f);
            float s2c = cx4.x * cx4.x + cx4.y * cx4.y + cx4.z * cx4.z;
            float kvo = __expf(-0.5f * oxy) * (0.9f * __expf(-50.0f * s2c) + 0.1f);
            acc = (float)n_oob * kvo;
        }
    }

    // ---- 15 symmetric pair terms for this group's offsets, doubled ----
    float accp = 0.0f;
    #pragma unroll
    for (int t = 0; t < PPG; t++) {
        int k = g * PPG + t;         // wave-uniform -> LDS broadcast reads
        int pk = s_pk[k];
        float e1 = s_e1[k];
        int di = pk >> 8, dj = (pk & 255) - 8;
        int p = cp + di * PT_W + dj;
        float4 xq = *(const float4*)&sx[p * 4];
        float dot = xq.w * cx4.w;    // y channel 20
        #pragma unroll
        for (int q = 0; q < 5; q++) {
            float4 tt = *(const float4*)&sy[p * 20 + q * 4];
            dot += tt.x * yc[q * 4 + 0] + tt.y * yc[q * 4 + 1] +
                   tt.z * yc[q * 4 + 2] + tt.w * yc[q * 4 + 3];
        }
        float d0 = xq.x - cx4.x, d1 = xq.y - cx4.y, d2 = xq.z - cx4.z;
        float s2 = d0 * d0 + d1 * d1 + d2 * d2;
        bool inb = ((h + di) < IMG_H) && ((unsigned)(w + dj) < (unsigned)IMG_W);
        float e = inb ? e1 : 0.0f;   // OOB handled by analytic fold
        float kv = e * (0.9f * __expf(-50.0f * s2) + 0.1f);
        accp += kv * (1.0f - dot);
    }

    float total = acc + 2.0f * accp;

    // block reduce -> one atomic per block
    #pragma unroll
    for (int s = 32; s > 0; s >>= 1) total += __shfl_down(total, s, 64);
    if ((tid & 63) == 0) s_red[tid >> 6] = total;
    __syncthreads();
    if (tid == 0) {
        float bs = 0.0f;
        #pragma unroll
        for (int wv = 0; wv < NTHREADS / 64; wv++) bs += s_red[wv];
        atomicAdd(out, bs * (1.0f / (float)(N_IMG * HW)));
    }
}

extern "C" void kernel_launch(void* const* d_in, const int* in_sizes, int n_in,
                              void* d_out, int out_size, void* d_ws, size_t ws_size,
                              hipStream_t stream) {
    const float* x = (const float*)d_in[0];
    const float* y = (const float*)d_in[1];
    float* out = (float*)d_out;
    hipMemsetAsync(out, 0, sizeof(float), stream);
    dim3 grid(IMG_W / TILE_W, IMG_H / TILE_H, N_IMG);  // (8,16,4) = 512 blocks
    gcrf_kernel<<<grid, NTHREADS, 0, stream>>>(x, y, out);
}